// Round 5
// baseline (164.033 us; speedup 1.0000x reference)
//
#include <hip/hip_runtime.h>

// UpsampleFlow2: Gaussian Nadaraya-Watson upsampling.
// out [B,3,N] = (sum_s k*f)/(sum_s k), k = exp(-|x-y|^2/r^2).
// exp(-|x|^2/r^2) cancels in num/den ->
//   k' = exp2( fma(px,ax, fma(py,ay, fma(pz,az, aw))) )
//   with a = (c2*yx, c2*yy, c2*yz, cy*|y|^2), c2=2*log2e/r^2, cy=-log2e/r^2.
//
// R5: INSTRUMENTATION ROUND. R1-R4 (32-38us) never showed our kernel in the
// rocprof top-5 (256MiB ws-poison fills at ~40us own it). Repeat the inner
// loop REPS=10x in-kernel: num and den both scale by REPS -> ratio unchanged,
// and the main kernel becomes the top dispatch with real counters.
// Also: PPT=8 scalar (half the per-pair ds_reads of R1), CHUNK=32/SC=64
// -> 1024 blocks = 4 waves/SIMD.

constexpr int B_ = 4, N_ = 8192, S_ = 2048;
constexpr int BLOCK = 256, PPT = 8, REPS = 10;
constexpr int PTS_PER_BLOCK = BLOCK * PPT;      // 2048
constexpr int NBPB = N_ / PTS_PER_BLOCK;        // 4
constexpr int NB = B_ * NBPB;                   // 16
constexpr int BN = B_ * N_;                     // 32768
constexpr float LOG2E = 1.4426950408889634f;

template <int CHUNK>
__global__ __launch_bounds__(BLOCK, 4) void uf2_main_r(
    const float* __restrict__ xyz,
    const float* __restrict__ sxyz,
    const float* __restrict__ sflow,
    const int* __restrict__ resol,
    float4* __restrict__ part)
{
    __shared__ float4 As[CHUNK];   // (c2*yx, c2*yy, c2*yz, cy*|y|^2)
    __shared__ float4 Fs[CHUNK];   // (fx, fy, fz, unused)

    const int nb = blockIdx.x % NB;
    const int sc = blockIdx.x / NB;
    const int b  = nb / NBPB;
    const int n0 = (nb % NBPB) * PTS_PER_BLOCK;
    const int s0 = sc * CHUNK;

    const float r = (float)resol[0];            // INITIAL_RADIUS(=1)*resol
    const float inv_r2 = 1.0f / (r * r);
    const float c2 = 2.0f * inv_r2 * LOG2E;
    const float cy = -inv_r2 * LOG2E;

    // ---- stage + pack sparse chunk into LDS ----
    const float* yb = sxyz  + b * 3 * S_;
    const float* fb = sflow + b * 3 * S_;
    for (int t = threadIdx.x; t < CHUNK; t += BLOCK) {
        const int s = s0 + t;
        const float yx = yb[s], yy = yb[S_ + s], yz = yb[2 * S_ + s];
        const float fx = fb[s], fy = fb[S_ + s], fz = fb[2 * S_ + s];
        As[t] = make_float4(c2 * yx, c2 * yy, c2 * yz,
                            cy * (yx * yx + yy * yy + yz * yz));
        Fs[t] = make_float4(fx, fy, fz, 0.0f);
    }
    __syncthreads();

    // ---- per-thread query points ----
    const float* xb = xyz + b * 3 * N_;
    float px[PPT], py[PPT], pz[PPT];
    float ax[PPT], ay[PPT], az[PPT], aw[PPT];
#pragma unroll
    for (int p = 0; p < PPT; ++p) {
        const int n = n0 + threadIdx.x + p * BLOCK;
        px[p] = xb[n]; py[p] = xb[N_ + n]; pz[p] = xb[2 * N_ + n];
        ax[p] = 0.f; ay[p] = 0.f; az[p] = 0.f; aw[p] = 0.f;
    }

    // ---- REPS x main loop; accumulating across reps scales num AND den
    //      by REPS, which cancels in num/den. Launder px/py/pz per rep so
    //      the compiler cannot CSE the repeated computation.
#pragma unroll 1
    for (int rep = 0; rep < REPS; ++rep) {
#pragma unroll
        for (int p = 0; p < PPT; ++p) {
            asm volatile("" : "+v"(px[p]), "+v"(py[p]), "+v"(pz[p]));
        }
#pragma unroll 2
        for (int t = 0; t < CHUNK; ++t) {
            const float4 a = As[t];   // broadcast ds_read_b128
            const float4 f = Fs[t];
#pragma unroll
            for (int p = 0; p < PPT; ++p) {
                float e = fmaf(pz[p], a.z, a.w);
                e = fmaf(py[p], a.y, e);
                e = fmaf(px[p], a.x, e);
                const float k = __builtin_amdgcn_exp2f(e);
                ax[p] = fmaf(k, f.x, ax[p]);
                ay[p] = fmaf(k, f.y, ay[p]);
                az[p] = fmaf(k, f.z, az[p]);
                aw[p] += k;
            }
        }
    }

    // ---- write partials (coalesced float4) ----
#pragma unroll
    for (int p = 0; p < PPT; ++p) {
        const int g = b * N_ + n0 + threadIdx.x + p * BLOCK;
        part[(size_t)sc * BN + g] = make_float4(ax[p], ay[p], az[p], aw[p]);
    }
}

__global__ __launch_bounds__(BLOCK) void uf2_combine(
    const float4* __restrict__ part, float* __restrict__ out, int SC)
{
    const int g = blockIdx.x * BLOCK + threadIdx.x;   // 0..BN-1
    float4 s = make_float4(0.f, 0.f, 0.f, 0.f);
    for (int c = 0; c < SC; ++c) {
        const float4 p = part[(size_t)c * BN + g];
        s.x += p.x; s.y += p.y; s.z += p.z; s.w += p.w;
    }
    const float inv = 1.0f / s.w;
    const int b = g >> 13;            // /8192
    const int n = g & (N_ - 1);
    float* ob = out + b * 3 * N_;
    ob[n]          = s.x * inv;
    ob[N_ + n]     = s.y * inv;
    ob[2 * N_ + n] = s.z * inv;
}

// Fallback (ws too small): single kernel, full S staged in LDS, direct out.
__global__ __launch_bounds__(BLOCK, 1) void uf2_fused(
    const float* __restrict__ xyz,
    const float* __restrict__ sxyz,
    const float* __restrict__ sflow,
    const int* __restrict__ resol,
    float* __restrict__ out)
{
    constexpr int FPPT = 4;
    constexpr int PTS = BLOCK * FPPT;
    __shared__ float4 As[S_];
    __shared__ float4 Fs[S_];

    const int nb = blockIdx.x;
    const int b  = nb / (N_ / PTS);
    const int n0 = (nb % (N_ / PTS)) * PTS;

    const float r = (float)resol[0];
    const float inv_r2 = 1.0f / (r * r);
    const float c2 = 2.0f * inv_r2 * LOG2E;
    const float cy = -inv_r2 * LOG2E;

    const float* yb = sxyz  + b * 3 * S_;
    const float* fb = sflow + b * 3 * S_;
    for (int t = threadIdx.x; t < S_; t += BLOCK) {
        const float yx = yb[t], yy = yb[S_ + t], yz = yb[2 * S_ + t];
        const float fx = fb[t], fy = fb[S_ + t], fz = fb[2 * S_ + t];
        As[t] = make_float4(c2 * yx, c2 * yy, c2 * yz,
                            cy * (yx * yx + yy * yy + yz * yz));
        Fs[t] = make_float4(fx, fy, fz, 0.0f);
    }
    __syncthreads();

    const float* xb = xyz + b * 3 * N_;
    float px[FPPT], py[FPPT], pz[FPPT];
    float4 acc[FPPT];
#pragma unroll
    for (int p = 0; p < FPPT; ++p) {
        const int n = n0 + threadIdx.x + p * BLOCK;
        px[p] = xb[n]; py[p] = xb[N_ + n]; pz[p] = xb[2 * N_ + n];
        acc[p] = make_float4(0.f, 0.f, 0.f, 0.f);
    }
#pragma unroll 4
    for (int t = 0; t < S_; ++t) {
        const float4 a = As[t];
        const float4 f = Fs[t];
#pragma unroll
        for (int p = 0; p < FPPT; ++p) {
            float e = fmaf(pz[p], a.z, a.w);
            e = fmaf(py[p], a.y, e);
            e = fmaf(px[p], a.x, e);
            const float k = __builtin_amdgcn_exp2f(e);
            acc[p].x = fmaf(k, f.x, acc[p].x);
            acc[p].y = fmaf(k, f.y, acc[p].y);
            acc[p].z = fmaf(k, f.z, acc[p].z);
            acc[p].w += k;
        }
    }
#pragma unroll
    for (int p = 0; p < FPPT; ++p) {
        const int n = n0 + threadIdx.x + p * BLOCK;
        const float inv = 1.0f / acc[p].w;
        float* ob = out + b * 3 * N_;
        ob[n]          = acc[p].x * inv;
        ob[N_ + n]     = acc[p].y * inv;
        ob[2 * N_ + n] = acc[p].z * inv;
    }
}

extern "C" void kernel_launch(void* const* d_in, const int* in_sizes, int n_in,
                              void* d_out, int out_size, void* d_ws, size_t ws_size,
                              hipStream_t stream)
{
    const float* xyz   = (const float*)d_in[0];
    const float* sxyz  = (const float*)d_in[1];
    const float* sflow = (const float*)d_in[2];
    const int*   resol = (const int*)d_in[3];
    float* out = (float*)d_out;
    float4* part = (float4*)d_ws;

    const size_t per_chunk = (size_t)BN * sizeof(float4);   // 512 KB
    int SC = 64;
    while (SC > 8 && (size_t)SC * per_chunk > ws_size) SC >>= 1;

    if ((size_t)SC * per_chunk > ws_size) {
        uf2_fused<<<dim3(BN / 1024), dim3(BLOCK), 0, stream>>>(
            xyz, sxyz, sflow, resol, out);
        return;
    }

    dim3 grid(NB * SC), blk(BLOCK);
    switch (SC) {
        case 64: uf2_main_r<S_ / 64><<<grid, blk, 0, stream>>>(xyz, sxyz, sflow, resol, part); break;
        case 32: uf2_main_r<S_ / 32><<<grid, blk, 0, stream>>>(xyz, sxyz, sflow, resol, part); break;
        case 16: uf2_main_r<S_ / 16><<<grid, blk, 0, stream>>>(xyz, sxyz, sflow, resol, part); break;
        default: uf2_main_r<S_ / 8 ><<<grid, blk, 0, stream>>>(xyz, sxyz, sflow, resol, part); break;
    }
    uf2_combine<<<dim3(BN / BLOCK), dim3(BLOCK), 0, stream>>>(part, out, SC);
}

// Round 6
// 34.706 us; speedup vs baseline: 4.7264x; 4.7264x over previous
//
#include <hip/hip_runtime.h>

// UpsampleFlow2: Gaussian Nadaraya-Watson upsampling.
// out [B,3,N] = (sum_s k*f)/(sum_s k), k = exp(-|x-y|^2/r^2).
// exp(-|x|^2/r^2) cancels in num/den ->
//   k' = exp2( fma(px,ax, fma(py,ay, fma(pz,az, aw))) )
//   a = (c2*yx, c2*yy, c2*yz, cy*|y|^2), c2=2*log2e/r^2, cy=-log2e/r^2.
//
// R6: R5 instrumentation showed VALU-bound (VALUBusy 88%, HBM 2.6%, LDS
// conflicts 0). Halve VALU issue with v_pk_fma_f32: process SPARSE POINTS IN
// PAIRS. LDS stores pair-packed coefficients; query coords are splatted to
// both halves ONCE before the loop (loop-invariant -> no in-loop movs).
// Per 2 sparse pts/query: 7 pk_fma + 2 exp2 = ~30 cyc/wave vs 44 scalar.
// pk ops via inline asm (no scalarization risk).

typedef float v2f __attribute__((ext_vector_type(2)));

constexpr int B_ = 4, N_ = 8192, S_ = 2048;
constexpr int BLOCK = 256, PPT = 8;
constexpr int PTS_PER_BLOCK = BLOCK * PPT;      // 2048
constexpr int NBPB = N_ / PTS_PER_BLOCK;        // 4
constexpr int NB = B_ * NBPB;                   // 16
constexpr int BN = B_ * N_;                     // 32768
constexpr float LOG2E = 1.4426950408889634f;

#define PK_FMA(d, a, b, c) \
    asm("v_pk_fma_f32 %0, %1, %2, %3" : "=v"(d) : "v"(a), "v"(b), "v"(c))
#define PK_FMA_ACC(acc, a, b) \
    asm("v_pk_fma_f32 %0, %1, %2, %0" : "+v"(acc) : "v"(a), "v"(b))
#define PK_ADD_ACC(acc, a) \
    asm("v_pk_add_f32 %0, %1, %0" : "+v"(acc) : "v"(a))

template <int CHUNK>
__global__ __launch_bounds__(BLOCK, 2) void uf2_main(
    const float* __restrict__ xyz,
    const float* __restrict__ sxyz,
    const float* __restrict__ sflow,
    const int* __restrict__ resol,
    float4* __restrict__ part)
{
    constexpr int TP = CHUNK / 2;      // sparse pairs per chunk
    __shared__ float4 AXY[TP];         // (ax0, ax1, ay0, ay1)
    __shared__ float4 AZW[TP];         // (az0, az1, aw0, aw1)
    __shared__ float4 FXY[TP];         // (fx0, fx1, fy0, fy1)
    __shared__ v2f    FZ2[TP];         // (fz0, fz1)

    const int nb = blockIdx.x % NB;
    const int sc = blockIdx.x / NB;
    const int b  = nb / NBPB;
    const int n0 = (nb % NBPB) * PTS_PER_BLOCK;
    const int s0 = sc * CHUNK;

    const float r = (float)resol[0];            // INITIAL_RADIUS(=1)*resol
    const float inv_r2 = 1.0f / (r * r);
    const float c2 = 2.0f * inv_r2 * LOG2E;
    const float cy = -inv_r2 * LOG2E;

    // ---- stage + pair-pack sparse chunk into LDS ----
    const float* yb = sxyz  + b * 3 * S_;
    const float* fb = sflow + b * 3 * S_;
    for (int tp = threadIdx.x; tp < TP; tp += BLOCK) {
        const int s = s0 + 2 * tp;
        const float yx0 = yb[s],          yx1 = yb[s + 1];
        const float yy0 = yb[S_ + s],     yy1 = yb[S_ + s + 1];
        const float yz0 = yb[2 * S_ + s], yz1 = yb[2 * S_ + s + 1];
        const float fx0 = fb[s],          fx1 = fb[s + 1];
        const float fy0 = fb[S_ + s],     fy1 = fb[S_ + s + 1];
        const float fz0 = fb[2 * S_ + s], fz1 = fb[2 * S_ + s + 1];
        AXY[tp] = make_float4(c2 * yx0, c2 * yx1, c2 * yy0, c2 * yy1);
        AZW[tp] = make_float4(c2 * yz0, c2 * yz1,
                              cy * (yx0 * yx0 + yy0 * yy0 + yz0 * yz0),
                              cy * (yx1 * yx1 + yy1 * yy1 + yz1 * yz1));
        FXY[tp] = make_float4(fx0, fx1, fy0, fy1);
        FZ2[tp] = (v2f){fz0, fz1};
    }
    __syncthreads();

    // ---- per-thread query points, splatted once (loop-invariant) ----
    const float* xb = xyz + b * 3 * N_;
    v2f px2[PPT], py2[PPT], pz2[PPT];
    v2f acx[PPT], acy[PPT], acz[PPT], acw[PPT];
#pragma unroll
    for (int p = 0; p < PPT; ++p) {
        const int n = n0 + threadIdx.x + p * BLOCK;
        const float x = xb[n], y = xb[N_ + n], z = xb[2 * N_ + n];
        px2[p] = (v2f){x, x}; py2[p] = (v2f){y, y}; pz2[p] = (v2f){z, z};
        acx[p] = (v2f){0.f, 0.f}; acy[p] = (v2f){0.f, 0.f};
        acz[p] = (v2f){0.f, 0.f}; acw[p] = (v2f){0.f, 0.f};
    }

    // ---- main loop: 3.5 LDS reads + (7 pk_fma + 2 exp2) x PPT per pair ----
#pragma unroll 2
    for (int tp = 0; tp < TP; ++tp) {
        const float4 axy = AXY[tp];   // broadcast ds_read_b128
        const float4 azw = AZW[tp];
        const float4 fxy = FXY[tp];
        const v2f fz2 = FZ2[tp];
        const v2f ax2 = (v2f){axy.x, axy.y}, ay2 = (v2f){axy.z, axy.w};
        const v2f az2 = (v2f){azw.x, azw.y}, aw2 = (v2f){azw.z, azw.w};
        const v2f fx2 = (v2f){fxy.x, fxy.y}, fy2 = (v2f){fxy.z, fxy.w};
#pragma unroll
        for (int p = 0; p < PPT; ++p) {
            v2f e2;
            PK_FMA(e2, pz2[p], az2, aw2);
            PK_FMA_ACC(e2, py2[p], ay2);
            PK_FMA_ACC(e2, px2[p], ax2);
            v2f k2;
            k2.x = __builtin_amdgcn_exp2f(e2.x);
            k2.y = __builtin_amdgcn_exp2f(e2.y);
            PK_FMA_ACC(acx[p], k2, fx2);
            PK_FMA_ACC(acy[p], k2, fy2);
            PK_FMA_ACC(acz[p], k2, fz2);
            PK_ADD_ACC(acw[p], k2);
        }
    }

    // ---- reduce halves, write partials (coalesced float4) ----
#pragma unroll
    for (int p = 0; p < PPT; ++p) {
        const int g = b * N_ + n0 + threadIdx.x + p * BLOCK;
        part[(size_t)sc * BN + g] = make_float4(
            acx[p].x + acx[p].y, acy[p].x + acy[p].y,
            acz[p].x + acz[p].y, acw[p].x + acw[p].y);
    }
}

__global__ __launch_bounds__(BLOCK) void uf2_combine(
    const float4* __restrict__ part, float* __restrict__ out, int SC)
{
    const int g = blockIdx.x * BLOCK + threadIdx.x;   // 0..BN-1
    float4 s = make_float4(0.f, 0.f, 0.f, 0.f);
    for (int c = 0; c < SC; ++c) {
        const float4 p = part[(size_t)c * BN + g];
        s.x += p.x; s.y += p.y; s.z += p.z; s.w += p.w;
    }
    const float inv = 1.0f / s.w;
    const int b = g >> 13;            // /8192
    const int n = g & (N_ - 1);
    float* ob = out + b * 3 * N_;
    ob[n]          = s.x * inv;
    ob[N_ + n]     = s.y * inv;
    ob[2 * N_ + n] = s.z * inv;
}

// Fallback (ws too small): single kernel, full S staged in LDS, direct out.
__global__ __launch_bounds__(BLOCK, 1) void uf2_fused(
    const float* __restrict__ xyz,
    const float* __restrict__ sxyz,
    const float* __restrict__ sflow,
    const int* __restrict__ resol,
    float* __restrict__ out)
{
    constexpr int FPPT = 4;
    constexpr int PTS = BLOCK * FPPT;
    __shared__ float4 As[S_];
    __shared__ float4 Fs[S_];

    const int nb = blockIdx.x;
    const int b  = nb / (N_ / PTS);
    const int n0 = (nb % (N_ / PTS)) * PTS;

    const float r = (float)resol[0];
    const float inv_r2 = 1.0f / (r * r);
    const float c2 = 2.0f * inv_r2 * LOG2E;
    const float cy = -inv_r2 * LOG2E;

    const float* yb = sxyz  + b * 3 * S_;
    const float* fb = sflow + b * 3 * S_;
    for (int t = threadIdx.x; t < S_; t += BLOCK) {
        const float yx = yb[t], yy = yb[S_ + t], yz = yb[2 * S_ + t];
        const float fx = fb[t], fy = fb[S_ + t], fz = fb[2 * S_ + t];
        As[t] = make_float4(c2 * yx, c2 * yy, c2 * yz,
                            cy * (yx * yx + yy * yy + yz * yz));
        Fs[t] = make_float4(fx, fy, fz, 0.0f);
    }
    __syncthreads();

    const float* xb = xyz + b * 3 * N_;
    float px[FPPT], py[FPPT], pz[FPPT];
    float4 acc[FPPT];
#pragma unroll
    for (int p = 0; p < FPPT; ++p) {
        const int n = n0 + threadIdx.x + p * BLOCK;
        px[p] = xb[n]; py[p] = xb[N_ + n]; pz[p] = xb[2 * N_ + n];
        acc[p] = make_float4(0.f, 0.f, 0.f, 0.f);
    }
#pragma unroll 4
    for (int t = 0; t < S_; ++t) {
        const float4 a = As[t];
        const float4 f = Fs[t];
#pragma unroll
        for (int p = 0; p < FPPT; ++p) {
            float e = fmaf(pz[p], a.z, a.w);
            e = fmaf(py[p], a.y, e);
            e = fmaf(px[p], a.x, e);
            const float k = __builtin_amdgcn_exp2f(e);
            acc[p].x = fmaf(k, f.x, acc[p].x);
            acc[p].y = fmaf(k, f.y, acc[p].y);
            acc[p].z = fmaf(k, f.z, acc[p].z);
            acc[p].w += k;
        }
    }
#pragma unroll
    for (int p = 0; p < FPPT; ++p) {
        const int n = n0 + threadIdx.x + p * BLOCK;
        const float inv = 1.0f / acc[p].w;
        float* ob = out + b * 3 * N_;
        ob[n]          = acc[p].x * inv;
        ob[N_ + n]     = acc[p].y * inv;
        ob[2 * N_ + n] = acc[p].z * inv;
    }
}

extern "C" void kernel_launch(void* const* d_in, const int* in_sizes, int n_in,
                              void* d_out, int out_size, void* d_ws, size_t ws_size,
                              hipStream_t stream)
{
    const float* xyz   = (const float*)d_in[0];
    const float* sxyz  = (const float*)d_in[1];
    const float* sflow = (const float*)d_in[2];
    const int*   resol = (const int*)d_in[3];
    float* out = (float*)d_out;
    float4* part = (float4*)d_ws;

    const size_t per_chunk = (size_t)BN * sizeof(float4);   // 512 KB
    int SC = 32;
    while (SC > 1 && (size_t)SC * per_chunk > ws_size) SC >>= 1;

    if ((size_t)SC * per_chunk > ws_size) {
        uf2_fused<<<dim3(BN / 1024), dim3(BLOCK), 0, stream>>>(
            xyz, sxyz, sflow, resol, out);
        return;
    }

    dim3 grid(NB * SC), blk(BLOCK);
    switch (SC) {
        case 32: uf2_main<S_ / 32><<<grid, blk, 0, stream>>>(xyz, sxyz, sflow, resol, part); break;
        case 16: uf2_main<S_ / 16><<<grid, blk, 0, stream>>>(xyz, sxyz, sflow, resol, part); break;
        case 8:  uf2_main<S_ / 8 ><<<grid, blk, 0, stream>>>(xyz, sxyz, sflow, resol, part); break;
        case 4:  uf2_main<S_ / 4 ><<<grid, blk, 0, stream>>>(xyz, sxyz, sflow, resol, part); break;
        case 2:  uf2_main<S_ / 2 ><<<grid, blk, 0, stream>>>(xyz, sxyz, sflow, resol, part); break;
        default: uf2_main<S_     ><<<grid, blk, 0, stream>>>(xyz, sxyz, sflow, resol, part); break;
    }
    uf2_combine<<<dim3(BN / BLOCK), dim3(BLOCK), 0, stream>>>(part, out, SC);
}